// Round 1
// baseline (26.604 us; speedup 1.0000x reference)
//
#include <hip/hip_runtime.h>

#define NSCALE 16
#define NV 64  // 4 * NSCALE accumulated values per output point

__global__ __launch_bounds__(256) void sph_pool_kernel(
    const float* __restrict__ f,
    const float* __restrict__ coords,
    const float* __restrict__ out_coords,
    const float* __restrict__ mu,
    const float* __restrict__ r_norms,
    const float* __restrict__ a_norms_0,
    const float* __restrict__ a_norms_1,
    float* __restrict__ out,
    int N, int A)
{
    const int lane = threadIdx.x & 63;
    const int wave = threadIdx.x >> 6;   // 0..3
    const int pair = wave >> 1;          // which output point within block (0..1)
    const int half = wave & 1;           // which i-half this wave handles
    const int a = blockIdx.x * 2 + pair;
    const bool active = (a < A);

    __shared__ float red[2][64];

    float acc[NV];
#pragma unroll
    for (int j = 0; j < NV; ++j) acc[j] = 0.0f;

    if (active) {
        const float ox = out_coords[3 * a + 0];
        const float oy = out_coords[3 * a + 1];
        const float oz = out_coords[3 * a + 2];

        float negmu[NSCALE];
#pragma unroll
        for (int s = 0; s < NSCALE; ++s) negmu[s] = -mu[s];

        for (int i = lane + half * 64; i < N; i += 128) {
            const float fi = f[i];
            const float dx = coords[3 * i + 0] - ox;
            const float dy = coords[3 * i + 1] - oy;
            const float dz = coords[3 * i + 2] - oz;
            const float r2 = dx * dx + dy * dy + dz * dz;
            const float rinv = rsqrtf(r2);     // v_rsq_f32
            const float r  = r2 * rinv;        // r = r2 / sqrt(r2)
            const float ux = dx * rinv;
            const float uy = dy * rinv;
            const float uz = dz * rinv;
#pragma unroll
            for (int s = 0; s < NSCALE; ++s) {
                const float e = __expf(negmu[s] * r);  // mul + v_exp_f32
                const float w = fi * e;
                acc[4 * s + 0] += w;
                acc[4 * s + 1] += w * ux;
                acc[4 * s + 2] += w * uy;
                acc[4 * s + 3] += w * uz;
            }
        }

        // Value-splitting butterfly reduce: 63 shuffles total.
        // Descending masks -> lane l ends holding the full sum of value index l.
#pragma unroll
        for (int m = 32; m >= 1; m >>= 1) {
            const bool hi = (lane & m) != 0;
#pragma unroll
            for (int j = 0; j < m; ++j) {
                const float lo_v = acc[j];
                const float hi_v = acc[j + m];
                const float give = hi ? lo_v : hi_v;
                const float keep = hi ? hi_v : lo_v;
                acc[j] = keep + __shfl_xor(give, m, 64);
            }
        }

        if (half == 1) red[pair][lane] = acc[0];
    }

    __syncthreads();

    if (active && half == 0) {
        const float v = acc[0] + red[pair][lane];
        const int s = lane >> 2;
        const int c = lane & 3;
        float scale;
        int idx;
        if (c == 0) {
            scale = r_norms[s] * a_norms_0[0];
            idx = a * (4 * NSCALE) + s;
        } else {
            scale = r_norms[s] * a_norms_1[c - 1];
            idx = a * (4 * NSCALE) + NSCALE + 3 * s + (c - 1);
        }
        out[idx] = v * scale;
    }
}

extern "C" void kernel_launch(void* const* d_in, const int* in_sizes, int n_in,
                              void* d_out, int out_size, void* d_ws, size_t ws_size,
                              hipStream_t stream) {
    const float* f          = (const float*)d_in[0];
    const float* coords     = (const float*)d_in[1];
    const float* out_coords = (const float*)d_in[2];
    const float* mu         = (const float*)d_in[3];
    const float* r_norms    = (const float*)d_in[4];
    const float* a_norms_0  = (const float*)d_in[5];
    const float* a_norms_1  = (const float*)d_in[6];
    float* out = (float*)d_out;

    const int N = in_sizes[0];       // B=1, f is [B,N]
    const int A = in_sizes[2] / 3;   // out_coords is [B,A,3]

    const int blocks = (A + 1) / 2;  // 2 output points per block (one per wave-pair)
    sph_pool_kernel<<<blocks, 256, 0, stream>>>(f, coords, out_coords, mu, r_norms,
                                                a_norms_0, a_norms_1, out, N, A);
}

// Round 2
// 24.413 us; speedup vs baseline: 1.0898x; 1.0898x over previous
//
#include <hip/hip_runtime.h>

#define NSCALE 16
#define SH 8   // scales per wave (scale-half)
#define NV 32  // 4 * SH accumulated values per wave

#if __has_builtin(__builtin_amdgcn_exp2f)
#define EXP2(x) __builtin_amdgcn_exp2f(x)
#else
#define EXP2(x) exp2f(x)
#endif
#if __has_builtin(__builtin_amdgcn_rsqf)
#define RSQ(x) __builtin_amdgcn_rsqf(x)
#else
#define RSQ(x) rsqrtf(x)
#endif

__global__ __launch_bounds__(256, 6) void sph_pool_kernel(
    const float* __restrict__ f,
    const float* __restrict__ coords,
    const float* __restrict__ out_coords,
    const float* __restrict__ mu,
    const float* __restrict__ r_norms,
    const float* __restrict__ a_norms_0,
    const float* __restrict__ a_norms_1,
    float* __restrict__ out,
    int N, int A)
{
    const int lane = threadIdx.x & 63;
    const int wave = threadIdx.x >> 6;   // 0..3
    const int sh   = wave >> 1;          // scale-half: s in [sh*8, sh*8+8)
    const int ih   = wave & 1;           // i-half
    const int a    = blockIdx.x;

    __shared__ float red[4][NV];

    float acc[NV];
#pragma unroll
    for (int j = 0; j < NV; ++j) acc[j] = 0.0f;

    const float ox = out_coords[3 * a + 0];
    const float oy = out_coords[3 * a + 1];
    const float oz = out_coords[3 * a + 2];

    // c[s] = -mu_s * log2(e): one mul + one v_exp_f32 per (i,s)
    float c[SH];
#pragma unroll
    for (int s = 0; s < SH; ++s)
        c[s] = mu[sh * SH + s] * (-1.44269504088896340736f);

    // software-pipelined i-loop: loads for iteration k+1 in flight during k
    int i = lane + (ih << 6);
    bool valid = (i < N);
    float fi = 0.f, cx = 0.f, cy = 0.f, cz = 0.f;
    if (valid) {
        fi = f[i];
        cx = coords[3 * i + 0];
        cy = coords[3 * i + 1];
        cz = coords[3 * i + 2];
    }
    while (valid) {
        const int inext = i + 128;
        const bool vnext = (inext < N);
        float fn = 0.f, nx = 0.f, ny = 0.f, nz = 0.f;
        if (vnext) {
            fn = f[inext];
            nx = coords[3 * inext + 0];
            ny = coords[3 * inext + 1];
            nz = coords[3 * inext + 2];
        }

        const float dx = cx - ox, dy = cy - oy, dz = cz - oz;
        const float r2 = dx * dx + dy * dy + dz * dz;
        const float rinv = RSQ(r2);          // v_rsq_f32
        const float r  = r2 * rinv;
        const float fr = fi * rinv;
        const float fx = fr * dx, fy = fr * dy, fz = fr * dz;
#pragma unroll
        for (int s = 0; s < SH; ++s) {
            const float e = EXP2(c[s] * r);  // v_mul + v_exp_f32
            acc[4 * s + 0] = fmaf(fi, e, acc[4 * s + 0]);
            acc[4 * s + 1] = fmaf(fx, e, acc[4 * s + 1]);
            acc[4 * s + 2] = fmaf(fy, e, acc[4 * s + 2]);
            acc[4 * s + 3] = fmaf(fz, e, acc[4 * s + 3]);
        }

        i = inext; valid = vnext;
        fi = fn; cx = nx; cy = ny; cz = nz;
    }

    // value-splitting butterfly over 32 values within each 32-lane half
    // (masks 16..1), then combine halves. Lane l ends with value (l&31).
#pragma unroll
    for (int m = 16; m >= 1; m >>= 1) {
        const bool hi = (lane & m) != 0;
#pragma unroll
        for (int j = 0; j < m; ++j) {
            const float lo_v = acc[j];
            const float hi_v = acc[j + m];
            const float give = hi ? lo_v : hi_v;
            const float keep = hi ? hi_v : lo_v;
            acc[j] = keep + __shfl_xor(give, m, 64);
        }
    }
    const float tot = acc[0] + __shfl_xor(acc[0], 32, 64);

    if (lane < NV) red[wave][lane] = tot;
    __syncthreads();

    // wave 0 combines the two i-halves and writes all 64 outputs for this a
    if (threadIdx.x < 64) {
        const int l  = threadIdx.x;
        const int so = l >> 5;        // which scale-half
        const int v  = l & 31;        // value index within half
        const float sum = red[so * 2 + 0][v] + red[so * 2 + 1][v];
        const int sl = v >> 2;        // scale within half
        const int cc = v & 3;         // 0 = scalar, 1..3 = x/y/z
        const int s  = so * SH + sl;
        float scale; int idx;
        if (cc == 0) {
            scale = r_norms[s] * a_norms_0[0];
            idx = a * (4 * NSCALE) + s;
        } else {
            scale = r_norms[s] * a_norms_1[cc - 1];
            idx = a * (4 * NSCALE) + NSCALE + 3 * s + (cc - 1);
        }
        out[idx] = sum * scale;
    }
}

extern "C" void kernel_launch(void* const* d_in, const int* in_sizes, int n_in,
                              void* d_out, int out_size, void* d_ws, size_t ws_size,
                              hipStream_t stream) {
    const float* f          = (const float*)d_in[0];
    const float* coords     = (const float*)d_in[1];
    const float* out_coords = (const float*)d_in[2];
    const float* mu         = (const float*)d_in[3];
    const float* r_norms    = (const float*)d_in[4];
    const float* a_norms_0  = (const float*)d_in[5];
    const float* a_norms_1  = (const float*)d_in[6];
    float* out = (float*)d_out;

    const int N = in_sizes[0];       // f is [B=1, N]
    const int A = in_sizes[2] / 3;   // out_coords is [B=1, A, 3]

    sph_pool_kernel<<<A, 256, 0, stream>>>(f, coords, out_coords, mu, r_norms,
                                           a_norms_0, a_norms_1, out, N, A);
}

// Round 3
// 20.225 us; speedup vs baseline: 1.3154x; 1.2071x over previous
//
#include <hip/hip_runtime.h>

#define NSCALE 16

#if __has_builtin(__builtin_amdgcn_exp2f)
__device__ __forceinline__ float exp2fast(float x) { return __builtin_amdgcn_exp2f(x); }
#else
// __expf is guaranteed native on AMD: v_mul (x*log2e) + v_exp_f32
__device__ __forceinline__ float exp2fast(float x) { return __expf(x * 0.6931471805599453f); }
#endif
#if __has_builtin(__builtin_amdgcn_rsqf)
#define RSQ(x) __builtin_amdgcn_rsqf(x)
#else
#define RSQ(x) rsqrtf(x)
#endif

// Group A: local scale order {16,12,8,4,2,1,6,3} (s' denominators)
//   exps: e16, e12; squarings: e8=e16^2, e4=e8^2, e2=e4^2, e1=e2^2, e6=e12^2, e3=e6^2
//   global s-index nibble table {15,11,7,3,1,0,5,2} -> 0x250137BF
// Group B: local scale order {9,10,11,13,14,15,5,7}
//   exps: e9,e10,e11,e13,e14,e15; squarings: e5=e10^2, e7=e14^2
//   global s-index nibble table {8,9,10,12,13,14,4,6} -> 0x64EDCA98

template <int GRP>
__device__ __forceinline__ void compute_e(const float* k, float r, float e[8]) {
    if constexpr (GRP == 0) {
        e[0] = exp2fast(k[0] * r);   // e16
        e[1] = exp2fast(k[1] * r);   // e12
        e[2] = e[0] * e[0];          // e8
        e[3] = e[2] * e[2];          // e4
        e[4] = e[3] * e[3];          // e2
        e[5] = e[4] * e[4];          // e1
        e[6] = e[1] * e[1];          // e6
        e[7] = e[6] * e[6];          // e3
    } else {
        e[0] = exp2fast(k[0] * r);   // e9
        e[1] = exp2fast(k[1] * r);   // e10
        e[2] = exp2fast(k[2] * r);   // e11
        e[3] = exp2fast(k[3] * r);   // e13
        e[4] = exp2fast(k[4] * r);   // e14
        e[5] = exp2fast(k[5] * r);   // e15
        e[6] = e[1] * e[1];          // e5
        e[7] = e[4] * e[4];          // e7
    }
}

struct F3 { float x, y, z; };

template <int GRP>
__device__ __forceinline__ void inner_loop(
    const float* __restrict__ f, const F3* __restrict__ c3,
    float ox, float oy, float oz, const float* __restrict__ k,
    int N, int i0, float acc[32])
{
#define PAIR_BODY(IVAR)                                                        \
    {                                                                          \
        const float fi = f[IVAR];                                              \
        const F3 p = c3[IVAR];                                                 \
        const float dx = p.x - ox, dy = p.y - oy, dz = p.z - oz;               \
        const float r2 = fmaf(dx, dx, fmaf(dy, dy, dz * dz));                  \
        const float rinv = RSQ(r2);                                            \
        const float r = r2 * rinv;                                             \
        const float fr = fi * rinv;                                            \
        const float fx = fr * dx, fy = fr * dy, fz = fr * dz;                  \
        float e[8];                                                            \
        compute_e<GRP>(k, r, e);                                               \
        _Pragma("unroll")                                                      \
        for (int s = 0; s < 8; ++s) {                                          \
            acc[4 * s + 0] = fmaf(e[s], fi, acc[4 * s + 0]);                   \
            acc[4 * s + 1] = fmaf(e[s], fx, acc[4 * s + 1]);                   \
            acc[4 * s + 2] = fmaf(e[s], fy, acc[4 * s + 2]);                   \
            acc[4 * s + 3] = fmaf(e[s], fz, acc[4 * s + 3]);                   \
        }                                                                      \
    }

    const int niter = N >> 7;          // trips of stride 128
    int t = 0;
    for (; t + 1 < niter; t += 2) {    // unroll x2 for ILP
        const int ia = i0 + t * 128;
        const int ib = ia + 128;
        PAIR_BODY(ia);
        PAIR_BODY(ib);
    }
    for (; t < niter; ++t) {
        const int ia = i0 + t * 128;
        PAIR_BODY(ia);
    }
    const int itail = i0 + niter * 128;
    if (itail < N) PAIR_BODY(itail);
#undef PAIR_BODY
}

__global__ __launch_bounds__(256, 4) void sph_pool_kernel(
    const float* __restrict__ f,
    const float* __restrict__ coords,
    const float* __restrict__ out_coords,
    const float* __restrict__ mu,
    const float* __restrict__ r_norms,
    const float* __restrict__ a_norms_0,
    const float* __restrict__ a_norms_1,
    float* __restrict__ out,
    int N, int A)
{
    const int lane = threadIdx.x & 63;
    const int wave = threadIdx.x >> 6;   // 0..3
    const int grp  = wave >> 1;          // 0 = group A, 1 = group B
    const int ih   = wave & 1;           // i-half
    const int a    = blockIdx.x;

    __shared__ float red[2][32];

    float acc[32];
#pragma unroll
    for (int j = 0; j < 32; ++j) acc[j] = 0.0f;

    const float ox = out_coords[3 * a + 0];
    const float oy = out_coords[3 * a + 1];
    const float oz = out_coords[3 * a + 2];

    const float L2E = 1.44269504088896340736f;
    float k[6];
    if (grp == 0) {
        k[0] = -L2E * mu[15];  // s'=16
        k[1] = -L2E * mu[11];  // s'=12
        k[2] = k[3] = k[4] = k[5] = 0.f;
    } else {
        k[0] = -L2E * mu[8];   // s'=9
        k[1] = -L2E * mu[9];   // s'=10
        k[2] = -L2E * mu[10];  // s'=11
        k[3] = -L2E * mu[12];  // s'=13
        k[4] = -L2E * mu[13];  // s'=14
        k[5] = -L2E * mu[14];  // s'=15
    }

    const F3* c3 = (const F3*)coords;
    const int i0 = lane + (ih << 6);
    if (grp == 0) inner_loop<0>(f, c3, ox, oy, oz, k, N, i0, acc);
    else          inner_loop<1>(f, c3, ox, oy, oz, k, N, i0, acc);

    // value-splitting butterfly over 32 values within each 32-lane half
    // (masks 16..1), then combine the two halves. Lane l ends with value (l&31).
#pragma unroll
    for (int m = 16; m >= 1; m >>= 1) {
        const bool hi = (lane & m) != 0;
#pragma unroll
        for (int j = 0; j < m; ++j) {
            const float lo_v = acc[j];
            const float hi_v = acc[j + m];
            const float give = hi ? lo_v : hi_v;
            const float keep = hi ? hi_v : lo_v;
            acc[j] = keep + __shfl_xor(give, m, 64);
        }
    }
    const float tot = acc[0] + __shfl_xor(acc[0], 32, 64);

    if (ih == 1 && lane < 32) red[grp][lane] = tot;
    __syncthreads();

    if (ih == 0 && lane < 32) {
        const float sum = tot + red[grp][lane];
        const int sl = lane >> 2;      // local scale index 0..7
        const int cc = lane & 3;       // 0 = scalar, 1..3 = x/y/z
        const unsigned table = grp ? 0x64EDCA98u : 0x250137BFu;
        const int s = (table >> (sl * 4)) & 0xF;
        float scale; int idx;
        if (cc == 0) {
            scale = r_norms[s] * a_norms_0[0];
            idx = a * (4 * NSCALE) + s;
        } else {
            scale = r_norms[s] * a_norms_1[cc - 1];
            idx = a * (4 * NSCALE) + NSCALE + 3 * s + (cc - 1);
        }
        out[idx] = sum * scale;
    }
}

extern "C" void kernel_launch(void* const* d_in, const int* in_sizes, int n_in,
                              void* d_out, int out_size, void* d_ws, size_t ws_size,
                              hipStream_t stream) {
    const float* f          = (const float*)d_in[0];
    const float* coords     = (const float*)d_in[1];
    const float* out_coords = (const float*)d_in[2];
    const float* mu         = (const float*)d_in[3];
    const float* r_norms    = (const float*)d_in[4];
    const float* a_norms_0  = (const float*)d_in[5];
    const float* a_norms_1  = (const float*)d_in[6];
    float* out = (float*)d_out;

    const int N = in_sizes[0];       // f is [B=1, N]
    const int A = in_sizes[2] / 3;   // out_coords is [B=1, A, 3]

    sph_pool_kernel<<<A, 256, 0, stream>>>(f, coords, out_coords, mu, r_norms,
                                           a_norms_0, a_norms_1, out, N, A);
}